// Round 4
// baseline (2002.581 us; speedup 1.0000x reference)
//
#include <hip/hip_runtime.h>

// ---------------------------------------------------------------------------
// DecoderBackbone: 4-layer llama-style decoder, B=2 T=1024 HID=2048,
// NH=16 NKV=4 HD=128, INTER=5632. fp32 residual stream, bf16 MFMA GEMMs.
// R4: attn causal-balance pairing + K-register double-buffer prefetch;
// QKV -> 8-phase split-K2 with fused bias/scatter reduce.
// ---------------------------------------------------------------------------

typedef __attribute__((ext_vector_type(8))) __bf16 bf16x8;
typedef __attribute__((ext_vector_type(4))) float f32x4;
typedef __attribute__((ext_vector_type(4))) unsigned short u16x4;

#define DEV __device__ __forceinline__

#define NTOK 2048     // B*T
#define HIDDIM 2048
#define NHEADS 16
#define NKVH 4
#define HDIM 128
#define KVDIM 512     // NKV*HD
#define INTERDIM 5632

DEV unsigned short f2bf(float f) {
  union { float f; unsigned u; } a; a.f = f;
  unsigned r = a.u + 0x7fffu + ((a.u >> 16) & 1u);   // RNE
  return (unsigned short)(r >> 16);
}
DEV float bf2f(unsigned short h) {
  union { unsigned u; float f; } a; a.u = ((unsigned)h) << 16;
  return a.f;
}
DEV void gload_lds16(const void* g, void* l) {
  __builtin_amdgcn_global_load_lds(
      (const __attribute__((address_space(1))) unsigned int*)(g),
      (__attribute__((address_space(3))) unsigned int*)(l), 16, 0, 0);
}

// ---------------------------------------------------------------------------
// fp32 -> bf16 weight convert, 8 elems/thread. n8 = n/8.
// ---------------------------------------------------------------------------
__global__ __launch_bounds__(256) void cvt_kernel(
    const float* __restrict__ in, unsigned short* __restrict__ out, int n8) {
  const int i = blockIdx.x * 256 + threadIdx.x;
  if (i >= n8) return;
  const f32x4* p = reinterpret_cast<const f32x4*>(in) + (size_t)i * 2;
  const f32x4 a = p[0], b = p[1];
  bf16x8 o;
  o[0] = (__bf16)a.x; o[1] = (__bf16)a.y; o[2] = (__bf16)a.z; o[3] = (__bf16)a.w;
  o[4] = (__bf16)b.x; o[5] = (__bf16)b.y; o[6] = (__bf16)b.z; o[7] = (__bf16)b.w;
  *reinterpret_cast<bf16x8*>(out + (size_t)i * 8) = o;
}

// ---------------------------------------------------------------------------
// RMSNorm: x fp32 [row][2048] -> out (bf16 or fp32), one block per row.
// ---------------------------------------------------------------------------
template <int OUTF32>
__global__ __launch_bounds__(256) void rmsnorm_kernel(
    const float* __restrict__ x, const float* __restrict__ w,
    void* __restrict__ outp) {
  const int row = blockIdx.x, tid = threadIdx.x;
  const int lane = tid & 63, wave = tid >> 6;
  const float* xr = x + (size_t)row * HIDDIM;
  f32x4 v0 = *reinterpret_cast<const f32x4*>(xr + tid * 4);
  f32x4 v1 = *reinterpret_cast<const f32x4*>(xr + 1024 + tid * 4);
  float ss = v0.x * v0.x + v0.y * v0.y + v0.z * v0.z + v0.w * v0.w +
             v1.x * v1.x + v1.y * v1.y + v1.z * v1.z + v1.w * v1.w;
#pragma unroll
  for (int off = 1; off < 64; off <<= 1) ss += __shfl_xor(ss, off, 64);
  __shared__ float red[4];
  if (lane == 0) red[wave] = ss;
  __syncthreads();
  ss = red[0] + red[1] + red[2] + red[3];
  const float rs = rsqrtf(ss * (1.0f / 2048.0f) + 1e-6f);
  f32x4 w0 = *reinterpret_cast<const f32x4*>(w + tid * 4);
  f32x4 w1 = *reinterpret_cast<const f32x4*>(w + 1024 + tid * 4);
  if (OUTF32) {
    float* o = (float*)outp + (size_t)row * HIDDIM;
    f32x4 o0, o1;
    o0.x = v0.x * rs * w0.x; o0.y = v0.y * rs * w0.y;
    o0.z = v0.z * rs * w0.z; o0.w = v0.w * rs * w0.w;
    o1.x = v1.x * rs * w1.x; o1.y = v1.y * rs * w1.y;
    o1.z = v1.z * rs * w1.z; o1.w = v1.w * rs * w1.w;
    *reinterpret_cast<f32x4*>(o + tid * 4) = o0;
    *reinterpret_cast<f32x4*>(o + 1024 + tid * 4) = o1;
  } else {
    unsigned short* o = (unsigned short*)outp + (size_t)row * HIDDIM;
    u16x4 p0, p1;
    p0.x = f2bf(v0.x * rs * w0.x); p0.y = f2bf(v0.y * rs * w0.y);
    p0.z = f2bf(v0.z * rs * w0.z); p0.w = f2bf(v0.w * rs * w0.w);
    p1.x = f2bf(v1.x * rs * w1.x); p1.y = f2bf(v1.y * rs * w1.y);
    p1.z = f2bf(v1.z * rs * w1.z); p1.w = f2bf(v1.w * rs * w1.w);
    *reinterpret_cast<u16x4*>(o + tid * 4) = p0;
    *reinterpret_cast<u16x4*>(o + 1024 + tid * 4) = p1;
  }
}

// ---------------------------------------------------------------------------
// 256x256 8-phase GEMM (T2+T3+T4+T5). C = A[M,K] * W[N,K]^T, bf16 in.
// EPI: 0=bf16(+bias), 2=silu(gate)*v bf16, 3=fp32 partial plane.
// ---------------------------------------------------------------------------
template <int MB>
DEV void mfma16(const bf16x8 (&aF)[4], const bf16x8 (&bF)[4],
                f32x4 (&acc)[8][4]) {
#pragma unroll
  for (int ni = 0; ni < 4; ++ni)
#pragma unroll
    for (int mi = 0; mi < 4; ++mi)
      acc[MB + mi][ni] = __builtin_amdgcn_mfma_f32_16x16x32_bf16(
          aF[mi], bF[ni], acc[MB + mi][ni], 0, 0, 0);
}

template <int EPI>
__global__ __launch_bounds__(512, 2) void gemm8p(
    const unsigned short* __restrict__ A, const unsigned short* __restrict__ W,
    const float* __restrict__ bias, unsigned short* __restrict__ outb,
    const unsigned short* __restrict__ gate, float* __restrict__ outf,
    int K, int ldo, int kt_split, int kt_tot, size_t zstride) {
  __shared__ unsigned short lds[65536];   // 128 KiB: [buf2][half4][128*64]
  const int tid = threadIdx.x, lane = tid & 63, wave = tid >> 6;
  const int fr = lane & 15, lq = lane >> 4;
  const int wm = wave >> 2, wn = wave & 3;

  int bx = blockIdx.x, by = blockIdx.y;
  {  // XCD-aware bijective swizzle within z-plane (nwg % 8 == 0 by construction)
    const int nbx = gridDim.x, nwg = nbx * gridDim.y;
    const int lin = by * nbx + bx, cpx = nwg >> 3;
    const int swz = (lin & 7) * cpx + (lin >> 3);
    bx = swz % nbx; by = swz / nbx;
  }
  const int m0 = by * 256, n0 = bx * 256;
  const int bz = blockIdx.z;
  const int t0 = bz * kt_split;
  int NT = kt_tot - t0; if (NT > kt_split) NT = kt_split;

  const int u0 = tid, u1 = tid + 512;
  const int r0s = u0 >> 3, r1s = u1 >> 3;
  const size_t off0 = (size_t)r0s * K + (size_t)((((u0 & 7) ^ (r0s & 7))) << 3);
  const size_t off1 = (size_t)r1s * K + (size_t)((((u1 & 7) ^ (r1s & 7))) << 3);
  const unsigned short* gb0 = A + (size_t)(m0)*K + (size_t)t0 * 64;
  const unsigned short* gb1 = A + (size_t)(m0 + 128) * K + (size_t)t0 * 64;
  const unsigned short* gb2 = W + (size_t)(n0)*K + (size_t)t0 * 64;
  const unsigned short* gb3 = W + (size_t)(n0 + 128) * K + (size_t)t0 * 64;

#define STAGE(h_, tt_, b_)                                                    \
  do {                                                                        \
    const unsigned short* _g =                                                \
        ((h_) == 0 ? gb0 : (h_) == 1 ? gb1 : (h_) == 2 ? gb2 : gb3) +         \
        (size_t)(tt_)*64;                                                     \
    unsigned short* _l = &lds[(b_)*32768 + (h_)*8192 + wave * 512];           \
    gload_lds16(_g + off0, _l);                                               \
    gload_lds16(_g + off1, _l + 4096);                                        \
  } while (0)

  const int e0 = lq ^ (fr & 7);
  const int cbA = wm * 8192;
  const int cbB = (2 + (wn >> 1)) * 8192;
  const int rB0 = (wn & 1) * 64 + fr;

#define LDA(mi_, ks_, c_)                                                     \
  (*reinterpret_cast<const bf16x8*>(                                          \
      &lds[(c_)*32768 + cbA + ((mi_)*16 + fr) * 64 + ((e0 ^ ((ks_)*4)) << 3)]))
#define LDB(ni_, ks_, c_)                                                     \
  (*reinterpret_cast<const bf16x8*>(                                          \
      &lds[(c_)*32768 + cbB + (rB0 + (ni_)*16) * 64 + ((e0 ^ ((ks_)*4)) << 3)]))

#define BARRIER() asm volatile("s_barrier" ::: "memory")

  f32x4 acc[8][4] = {};
  bf16x8 aF[4], bF[4];

  STAGE(0, 0, 0); STAGE(1, 0, 0); STAGE(2, 0, 0); STAGE(3, 0, 0);

  for (int t = 0; t < NT; ++t) {
    const int c = t & 1;
    if (t + 1 < NT) {
      STAGE(0, t + 1, c ^ 1);
      STAGE(2, t + 1, c ^ 1);
      asm volatile("s_waitcnt vmcnt(4)" ::: "memory");
    } else {
      asm volatile("s_waitcnt vmcnt(0)" ::: "memory");
    }
    BARRIER();

    bF[0] = LDB(0, 0, c); bF[1] = LDB(1, 0, c);
    bF[2] = LDB(2, 0, c); bF[3] = LDB(3, 0, c);
    aF[0] = LDA(0, 0, c); aF[1] = LDA(1, 0, c);
    aF[2] = LDA(2, 0, c); aF[3] = LDA(3, 0, c);
    if (t + 1 < NT) { STAGE(1, t + 1, c ^ 1); STAGE(3, t + 1, c ^ 1); }
    BARRIER();
    __builtin_amdgcn_s_setprio(1);
    mfma16<0>(aF, bF, acc);
    __builtin_amdgcn_s_setprio(0);
    __builtin_amdgcn_sched_barrier(0);
    BARRIER();

    aF[0] = LDA(4, 0, c); aF[1] = LDA(5, 0, c);
    aF[2] = LDA(6, 0, c); aF[3] = LDA(7, 0, c);
    BARRIER();
    __builtin_amdgcn_s_setprio(1);
    mfma16<4>(aF, bF, acc);
    __builtin_amdgcn_s_setprio(0);
    __builtin_amdgcn_sched_barrier(0);
    BARRIER();

    bF[0] = LDB(0, 1, c); bF[1] = LDB(1, 1, c);
    bF[2] = LDB(2, 1, c); bF[3] = LDB(3, 1, c);
    aF[0] = LDA(0, 1, c); aF[1] = LDA(1, 1, c);
    aF[2] = LDA(2, 1, c); aF[3] = LDA(3, 1, c);
    BARRIER();
    __builtin_amdgcn_s_setprio(1);
    mfma16<0>(aF, bF, acc);
    __builtin_amdgcn_s_setprio(0);
    __builtin_amdgcn_sched_barrier(0);
    BARRIER();

    aF[0] = LDA(4, 1, c); aF[1] = LDA(5, 1, c);
    aF[2] = LDA(6, 1, c); aF[3] = LDA(7, 1, c);
    BARRIER();
    __builtin_amdgcn_s_setprio(1);
    mfma16<4>(aF, bF, acc);
    __builtin_amdgcn_s_setprio(0);
    __builtin_amdgcn_sched_barrier(0);
    BARRIER();
  }

  const int r0 = lq * 4;
#pragma unroll
  for (int mi = 0; mi < 8; ++mi)
#pragma unroll
    for (int ni = 0; ni < 4; ++ni)
#pragma unroll
      for (int r = 0; r < 4; ++r) {
        const int gm = m0 + wm * 128 + mi * 16 + r0 + r;
        const int gn = n0 + wn * 64 + ni * 16 + fr;
        const float v = acc[mi][ni][r];
        if (EPI == 0) {
          float vv = v;
          if (bias) vv += bias[gn];
          outb[(size_t)gm * ldo + gn] = f2bf(vv);
        } else if (EPI == 2) {
          const float g = bf2f(gate[(size_t)gm * ldo + gn]);
          const float s = g / (1.f + __expf(-g));
          outb[(size_t)gm * ldo + gn] = f2bf(s * v);
        } else {
          outf[(size_t)bz * zstride + (size_t)gm * ldo + gn] = v;
        }
      }
#undef STAGE
#undef LDA
#undef LDB
#undef BARRIER
}

// x[i] += sum_{s<ks} p[s*zs4*4 + i]  (f32x4 lanes; n4 = n/4, zs4 = zstride/4)
__global__ __launch_bounds__(256) void reduce_addk(
    float* __restrict__ x, const float* __restrict__ p, int n4, int ks,
    size_t zs4) {
  const f32x4* pv = reinterpret_cast<const f32x4*>(p);
  f32x4* xv = reinterpret_cast<f32x4*>(x);
  for (int i = blockIdx.x * 256 + threadIdx.x; i < n4; i += gridDim.x * 256) {
    f32x4 s = pv[i];
    for (int sp = 1; sp < ks; ++sp) s += pv[(size_t)sp * zs4 + i];
    xv[i] += s;
  }
}

// QKV split-K2 reduce: sum 2 partial planes [2048][3072], add bias, write bf16
// scattered into q[2048,2048] / k[2048,512] / v[2048,512].
__global__ __launch_bounds__(256) void reduce_qkv(
    const float* __restrict__ p, const float* __restrict__ qb,
    const float* __restrict__ kb, const float* __restrict__ vb,
    unsigned short* __restrict__ qo, unsigned short* __restrict__ ko,
    unsigned short* __restrict__ vo) {
  const int i = blockIdx.x * 256 + threadIdx.x;   // < 1,572,864
  const int row = i / 768, c4 = (i - row * 768) * 4;
  const f32x4 a = *reinterpret_cast<const f32x4*>(p + (size_t)row * 3072 + c4);
  const f32x4 b =
      *reinterpret_cast<const f32x4*>(p + 6291456 + (size_t)row * 3072 + c4);
  const f32x4 s = a + b;
  const float* bias; unsigned short* out;
  if (c4 < 2048)      { bias = qb + c4;          out = qo + (size_t)row * 2048 + c4; }
  else if (c4 < 2560) { bias = kb + (c4 - 2048); out = ko + (size_t)row * 512 + (c4 - 2048); }
  else                { bias = vb + (c4 - 2560); out = vo + (size_t)row * 512 + (c4 - 2560); }
  u16x4 o;
  o.x = f2bf(s.x + bias[0]); o.y = f2bf(s.y + bias[1]);
  o.z = f2bf(s.z + bias[2]); o.w = f2bf(s.w + bias[3]);
  *reinterpret_cast<u16x4*>(out) = o;
}

// ---------------------------------------------------------------------------
// RoPE, in place on q (16 heads) and k (4 heads).
// ---------------------------------------------------------------------------
__global__ __launch_bounds__(256) void rope_kernel(
    unsigned short* __restrict__ q, unsigned short* __restrict__ k,
    const float* __restrict__ cosb, const float* __restrict__ sinb) {
  const int slot = blockIdx.x * 4 + (threadIdx.x >> 6);
  const int d = threadIdx.x & 63;
  const int tok = slot / 20, hs = slot % 20;
  unsigned short* base;
  if (hs < 16) base = q + (size_t)tok * HIDDIM + hs * HDIM;
  else         base = k + (size_t)tok * KVDIM + (hs - 16) * HDIM;
  const float c1 = cosb[(size_t)tok * HDIM + d];
  const float s1 = sinb[(size_t)tok * HDIM + d];
  const float c2 = cosb[(size_t)tok * HDIM + d + 64];
  const float s2 = sinb[(size_t)tok * HDIM + d + 64];
  const float x1 = bf2f(base[d]), x2 = bf2f(base[d + 64]);
  base[d]      = f2bf(x1 * c1 - x2 * s1);
  base[d + 64] = f2bf(x2 * c2 + x1 * s2);
}

// v[tok][kvh*128+d] -> vt[(b*4+kvh)*128+d][t]
__global__ __launch_bounds__(256) void transpose_v(
    const unsigned short* __restrict__ v, unsigned short* __restrict__ vt) {
  const int o = blockIdx.x * 256 + threadIdx.x;
  const int t = o & 1023;
  const int rest = o >> 10;
  const int d = rest & 127;
  const int bh = rest >> 7;
  const int kvh = bh & 3, b = bh >> 2;
  vt[o] = v[(size_t)(b * 1024 + t) * KVDIM + kvh * HDIM + d];
}

// ---------------------------------------------------------------------------
// Flash attention, causal, GQA. Block = 4 waves; wave owns 16 q-rows.
// R4: (1) causal-balance pairing: b=1 blocks take qt = 15 - blockIdx.x so
// each CU's two resident blocks sum to 17 kv-iterations; (2) K fragments
// double-buffered in registers — K(t+1) loads issue right after QK(t) MFMA
// and their latency hides under softmax(t)+PV(t).
// ---------------------------------------------------------------------------
__global__ __launch_bounds__(256) void attn_kernel(
    const unsigned short* __restrict__ q, const unsigned short* __restrict__ k,
    const unsigned short* __restrict__ vt, unsigned short* __restrict__ ao) {
  __shared__ unsigned short P_lds[4][1024];
  const int tid = threadIdx.x, lane = tid & 63, wave = tid >> 6;
  const int h = blockIdx.y, b = blockIdx.z;
  int qt = blockIdx.x;
  if (b) qt = 15 - qt;            // per-CU work pairing: (qt+1) + (16-qt) = 17
  const int kvh = h >> 2;
  const int q0 = qt * 64 + wave * 16;
  const int tokbase = b * 1024;
  const int fr = lane & 15, kq = (lane >> 4) * 8, r0 = (lane >> 4) * 4;

  bf16x8 aQ[4];
  {
    const unsigned short* qp =
        q + (size_t)(tokbase + q0 + fr) * HIDDIM + h * HDIM + kq;
#pragma unroll
    for (int ds = 0; ds < 4; ++ds)
      aQ[ds] = *reinterpret_cast<const bf16x8*>(qp + ds * 32);
  }
  float mrow[4], lrow[4];
#pragma unroll
  for (int r = 0; r < 4; ++r) { mrow[r] = -1e30f; lrow[r] = 0.f; }
  f32x4 accO[8] = {};
  const float scale = 0.08838834764831845f;
  const unsigned short* kbase = k + (size_t)tokbase * KVDIM + kvh * HDIM;
  const unsigned short* vbase = vt + (size_t)(b * 4 + kvh) * 128 * 1024;
  unsigned short* pw = &P_lds[wave][0];

  bf16x8 KA[4][4], KB[4][4];

  auto loadK = [&](bf16x8 (&dst)[4][4], int kb) {
    const unsigned short* kbp = kbase + (size_t)(kb * 64) * KVDIM;
#pragma unroll
    for (int cb = 0; cb < 4; ++cb) {
      const unsigned short* kr = kbp + (size_t)(cb * 16 + fr) * KVDIM + kq;
#pragma unroll
      for (int ds = 0; ds < 4; ++ds)
        dst[cb][ds] = *reinterpret_cast<const bf16x8*>(kr + ds * 32);
    }
  };

  auto step = [&](int kb, bf16x8 (&KF)[4][4], bf16x8 (&KN)[4][4]) {
    const int kv0 = kb * 64;
    f32x4 sacc[4] = {};
#pragma unroll
    for (int cb = 0; cb < 4; ++cb)
#pragma unroll
      for (int ds = 0; ds < 4; ++ds)
        sacc[cb] = __builtin_amdgcn_mfma_f32_16x16x32_bf16(aQ[ds], KF[cb][ds],
                                                           sacc[cb], 0, 0, 0);
    if (kb + 1 <= qt) loadK(KN, kb + 1);   // prefetch; consumed next step
    const bool maskblk = (kb == qt);
    float p[4][4];
#pragma unroll
    for (int r = 0; r < 4; ++r) {
      const int grow = q0 + r0 + r;
      float mx = -1e30f;
#pragma unroll
      for (int cb = 0; cb < 4; ++cb) {
        float s = sacc[cb][r] * scale;
        if (maskblk && (kv0 + cb * 16 + fr > grow)) s = -1e30f;
        p[cb][r] = s;
        mx = fmaxf(mx, s);
      }
#pragma unroll
      for (int off = 1; off < 16; off <<= 1)
        mx = fmaxf(mx, __shfl_xor(mx, off, 64));
      const float mn = fmaxf(mrow[r], mx);
      const float alpha = __expf(mrow[r] - mn);
      float sum = 0.f;
#pragma unroll
      for (int cb = 0; cb < 4; ++cb) {
        const float e = __expf(p[cb][r] - mn);
        p[cb][r] = e; sum += e;
      }
#pragma unroll
      for (int off = 1; off < 16; off <<= 1) sum += __shfl_xor(sum, off, 64);
      lrow[r] = lrow[r] * alpha + sum;
      mrow[r] = mn;
#pragma unroll
      for (int db = 0; db < 8; ++db) accO[db][r] *= alpha;
    }
#pragma unroll
    for (int cb = 0; cb < 4; ++cb)
#pragma unroll
      for (int r = 0; r < 4; ++r)
        pw[(r0 + r) * 64 + cb * 16 + fr] = f2bf(p[cb][r]);
    bf16x8 aP[2];
#pragma unroll
    for (int s2 = 0; s2 < 2; ++s2)
      aP[s2] = *reinterpret_cast<const bf16x8*>(pw + fr * 64 + s2 * 32 + kq);
#pragma unroll
    for (int db = 0; db < 8; ++db) {
      const unsigned short* vr = vbase + (size_t)(db * 16 + fr) * 1024 + kv0 + kq;
#pragma unroll
      for (int s2 = 0; s2 < 2; ++s2) {
        bf16x8 bV = *reinterpret_cast<const bf16x8*>(vr + s2 * 32);
        accO[db] =
            __builtin_amdgcn_mfma_f32_16x16x32_bf16(aP[s2], bV, accO[db], 0, 0, 0);
      }
    }
  };

  loadK(KA, 0);
  for (int kb = 0; kb <= qt; kb += 2) {
    step(kb, KA, KB);
    if (kb + 1 <= qt) step(kb + 1, KB, KA);
  }

  float invl[4];
#pragma unroll
  for (int r = 0; r < 4; ++r) invl[r] = 1.f / lrow[r];
#pragma unroll
  for (int db = 0; db < 8; ++db)
#pragma unroll
    for (int r = 0; r < 4; ++r)
      ao[(size_t)(tokbase + q0 + r0 + r) * HIDDIM + h * HDIM + db * 16 + fr] =
          f2bf(accO[db][r] * invl[r]);
}

// ---------------------------------------------------------------------------
extern "C" void kernel_launch(void* const* d_in, const int* in_sizes, int n_in,
                              void* d_out, int out_size, void* d_ws,
                              size_t ws_size, hipStream_t stream) {
  (void)in_sizes; (void)n_in; (void)out_size; (void)ws_size;
  const float* hidden = (const float*)d_in[0];
  const float* cosb  = (const float*)d_in[1];
  const float* sinb  = (const float*)d_in[2];
  const float* qw    = (const float*)d_in[3];
  const float* qbias = (const float*)d_in[4];
  const float* kw    = (const float*)d_in[5];
  const float* kbias = (const float*)d_in[6];
  const float* vw    = (const float*)d_in[7];
  const float* vbias = (const float*)d_in[8];
  const float* ow    = (const float*)d_in[9];
  const float* gw    = (const float*)d_in[10];
  const float* uw    = (const float*)d_in[11];
  const float* dw    = (const float*)d_in[12];
  const float* ln1   = (const float*)d_in[13];
  const float* ln2   = (const float*)d_in[14];
  const float* normw = (const float*)d_in[15];

  char* ws = (char*)d_ws;
  float* x               = (float*)ws;                          // 16,777,216 B
  unsigned short* hbuf   = (unsigned short*)(ws + 16777216);    //  8,388,608
  unsigned short* qbuf   = (unsigned short*)(ws + 25165824);    //  8,388,608
  unsigned short* kbuf   = (unsigned short*)(ws + 33554432);    //  2,097,152
  unsigned short* vbuf   = (unsigned short*)(ws + 35651584);    //  2,097,152
  unsigned short* vtbuf  = (unsigned short*)(ws + 37748736);    //  2,097,152
  unsigned short* aobuf  = (unsigned short*)(ws + 39845888);    //  8,388,608
  unsigned short* gatebuf= (unsigned short*)(ws + 48234496);    // 23,068,672
  unsigned short* actbuf = (unsigned short*)(ws + 71303168);    // 23,068,672
  unsigned short* wcvt   = (unsigned short*)(ws + 94371840);    // 23,068,672
  // total: 117,440,512 bytes
  //
  // Split-K fp32 partials reuse DEAD regions:
  //  - QKV  (KS=2, 50.3 MB): [vtbuf .. inside actbuf)  — dead during QKV.
  //  - O-proj (KS=2, 33.5 MB): [gatebuf ..)             — dead during O.
  //  - down   (KS=3, 50.3 MB): [hbuf .. inside gatebuf) — dead during down.
  float* pbufQKV = (float*)(ws + 37748736);
  float* pbufO   = (float*)(ws + 48234496);
  float* pbufD   = (float*)(ws + 16777216);

  unsigned short* wq16 = wcvt;                 // rows 0..2047   of [3072][2048]
  unsigned short* wk16 = wcvt + 4194304;       // rows 2048..2559
  unsigned short* wv16 = wcvt + 5242880;       // rows 2560..3071

  hipMemcpyAsync(x, hidden, (size_t)NTOK * HIDDIM * 4,
                 hipMemcpyDeviceToDevice, stream);

  for (int l = 0; l < 4; ++l) {
    const float* qw_l = qw + (size_t)l * 2048 * 2048;
    const float* qb_l = qbias + (size_t)l * 2048;
    const float* kw_l = kw + (size_t)l * 512 * 2048;
    const float* kb_l = kbias + (size_t)l * 512;
    const float* vw_l = vw + (size_t)l * 512 * 2048;
    const float* vb_l = vbias + (size_t)l * 512;
    const float* ow_l = ow + (size_t)l * 2048 * 2048;
    const float* gw_l = gw + (size_t)l * 5632 * 2048;
    const float* uw_l = uw + (size_t)l * 5632 * 2048;
    const float* dw_l = dw + (size_t)l * 2048 * 5632;

    rmsnorm_kernel<0><<<NTOK, 256, 0, stream>>>(x, ln1 + l * 2048, hbuf);
    cvt_kernel<<<2048, 256, 0, stream>>>(qw_l, wq16, 524288);
    cvt_kernel<<<512, 256, 0, stream>>>(kw_l, wk16, 131072);
    cvt_kernel<<<512, 256, 0, stream>>>(vw_l, wv16, 131072);
    // fused QKV: one [2048,2048] x [3072,2048]^T GEMM, split-K2 8-phase
    gemm8p<3><<<dim3(12, 8, 2), 512, 0, stream>>>(
        hbuf, wcvt, nullptr, nullptr, nullptr, pbufQKV, 2048, 3072, 16, 32,
        (size_t)6291456);
    reduce_qkv<<<6144, 256, 0, stream>>>(pbufQKV, qb_l, kb_l, vb_l, qbuf,
                                         kbuf, vbuf);
    rope_kernel<<<10240, 256, 0, stream>>>(qbuf, kbuf, cosb, sinb);
    transpose_v<<<4096, 256, 0, stream>>>(vbuf, vtbuf);
    attn_kernel<<<dim3(16, 16, 2), 256, 0, stream>>>(qbuf, kbuf, vtbuf, aobuf);

    // O-proj: split-K2 8-phase -> fp32 partials -> x += sum
    cvt_kernel<<<2048, 256, 0, stream>>>(ow_l, wcvt, 524288);
    gemm8p<3><<<dim3(8, 8, 2), 512, 0, stream>>>(
        aobuf, wcvt, nullptr, nullptr, nullptr, pbufO, 2048, 2048, 16, 32,
        (size_t)4194304);
    reduce_addk<<<2048, 256, 0, stream>>>(x, pbufO, 1048576, 2,
                                          (size_t)1048576);

    rmsnorm_kernel<0><<<NTOK, 256, 0, stream>>>(x, ln2 + l * 2048, hbuf);

    // gate
    cvt_kernel<<<5632, 256, 0, stream>>>(gw_l, wcvt, 1441792);
    gemm8p<0><<<dim3(22, 8, 1), 512, 0, stream>>>(
        hbuf, wcvt, nullptr, gatebuf, nullptr, nullptr, 2048, 5632, 32, 32,
        (size_t)0);
    // up (+ silu(gate) epilogue)
    cvt_kernel<<<5632, 256, 0, stream>>>(uw_l, wcvt, 1441792);
    gemm8p<2><<<dim3(22, 8, 1), 512, 0, stream>>>(
        hbuf, wcvt, nullptr, actbuf, gatebuf, nullptr, 2048, 5632, 32, 32,
        (size_t)0);
    // down: split-K3 -> fp32 partials -> x += sum
    cvt_kernel<<<5632, 256, 0, stream>>>(dw_l, wcvt, 1441792);
    gemm8p<3><<<dim3(8, 8, 3), 512, 0, stream>>>(
        actbuf, wcvt, nullptr, nullptr, nullptr, pbufD, 5632, 2048, 30, 88,
        (size_t)4194304);
    reduce_addk<<<2048, 256, 0, stream>>>(x, pbufD, 1048576, 3,
                                          (size_t)1048576);
  }
  rmsnorm_kernel<1><<<NTOK, 256, 0, stream>>>(x, normw, d_out);
}